// Round 4
// baseline (262.801 us; speedup 1.0000x reference)
//
#include <hip/hip_runtime.h>

#define B_  2048
#define T_  200
#define D_  128
#define H1_ 256
#define H2_ 128

typedef __attribute__((ext_vector_type(8))) short  s16x8;
typedef __attribute__((ext_vector_type(4))) float  f32x4;

// ws layout (bytes)
#define WS_WCF   0         // bf16 Wc frags: 256x256 -> 131072 B
#define WS_W2F   131072    // bf16 W2 frags: 256x128 -> 65536 B
#define WS_Q2    196608    // f32 (W1b - W1c): 128x256 -> 131072 B
#define WS_QB    327680    // f32 qb: 2048x256 -> 2097152 B

__device__ __forceinline__ unsigned short f2bf(float f) {
  union { float f; unsigned u; } v; v.f = f;
  unsigned r = v.u + 0x7fffu + ((v.u >> 16) & 1u);
  return (unsigned short)(r >> 16);
}
__device__ __forceinline__ float sigf(float x) {
  return __builtin_amdgcn_rcpf(1.0f + __expf(-x));
}

// ---------------- prep: weight fragments + Q2 ----------------
__global__ __launch_bounds__(256)
void prep_weights(const float* __restrict__ W1, const float* __restrict__ W2,
                  unsigned short* __restrict__ wcf, unsigned short* __restrict__ w2f,
                  float* __restrict__ Q2)
{
  int g = blockIdx.x * 256 + threadIdx.x;
  if (g < 8192) {
    int c = g >> 9, s = (g >> 6) & 7, l = g & 63;
    int col = 16 * c + (l & 15);
#pragma unroll
    for (int j = 0; j < 8; ++j) {
      int k = 32 * s + 8 * (l >> 4) + j;
      float v = W1[(256 + k) * H1_ + col];
      if (k < 128) v += W1[k * H1_ + col];
      wcf[(size_t)g * 8 + j] = f2bf(v);
    }
  } else if (g < 12288) {
    int g2 = g - 8192;
    int c = g2 >> 9, s = (g2 >> 6) & 7, l = g2 & 63;
    int col = 16 * c + (l & 15);
#pragma unroll
    for (int j = 0; j < 8; ++j) {
      int k = 32 * s + 8 * (l >> 4) + j;
      w2f[(size_t)g2 * 8 + j] = f2bf(W2[k * H2_ + col]);
    }
  } else {
    int g3 = g - 12288;
    int e = g3 * 4;
    int d = e >> 8, h = e & 255;
#pragma unroll
    for (int j = 0; j < 4; ++j)
      Q2[e + j] = W1[(128 + d) * H1_ + h + j] - W1[(256 + d) * H1_ + h + j];
  }
}

// ---------------- prep: qb[b][h] = b1[h] + q[b] @ Q2 ----------------
__global__ __launch_bounds__(256)
void qb_prep(const float* __restrict__ query, const float* __restrict__ b1,
             const float* __restrict__ Q2, float* __restrict__ qb)
{
  __shared__ float q8[8 * 128];
  int b0 = blockIdx.x * 8;
  int tid = threadIdx.x;
  {
    const float4 v = *(const float4*)(query + (size_t)b0 * 128 + tid * 4);
    *(float4*)(q8 + tid * 4) = v;
  }
  __syncthreads();
  int h = tid;
  float acc[8];
#pragma unroll
  for (int j = 0; j < 8; ++j) acc[j] = b1[h];
  for (int d = 0; d < 128; ++d) {
    float w = Q2[d * 256 + h];
#pragma unroll
    for (int j = 0; j < 8; ++j) acc[j] += q8[j * 128 + d] * w;
  }
#pragma unroll
  for (int j = 0; j < 8; ++j) qb[(size_t)(b0 + j) * 256 + h] = acc[j];
}

// ---------------- main ----------------
__global__ __launch_bounds__(512, 2)
void attn_main(const float* __restrict__ query, const float* __restrict__ keys,
               const int* __restrict__ mask,
               const unsigned short* __restrict__ wcf,
               const unsigned short* __restrict__ w2f,
               const float* __restrict__ qb_ws,
               const float* __restrict__ b2, const float* __restrict__ W3,
               const float* __restrict__ b3, float* __restrict__ out)
{
  __shared__ __align__(16) unsigned short Xc[64 * 256];   // 32KB swizzled
  __shared__ __align__(16) unsigned short H1c[64 * 256];  // 32KB swizzled
  __shared__ float qL[128];
  __shared__ float qbL[256];
  __shared__ float b2L[128];
  __shared__ float w3L[128];
  __shared__ float maskLf[256];
  __shared__ float ebuf[64];
  __shared__ float numred[8][128];
  __shared__ float denred[8];

  const int b = blockIdx.x;
  const int tid = threadIdx.x;
  const int lane = tid & 63;
  const int wid = tid >> 6;

  if (tid < 128) {
    qL[tid]  = query[(size_t)b * 128 + tid];
    b2L[tid] = b2[tid];
    w3L[tid] = W3[tid];
  }
  if (tid < 256) {
    qbL[tid] = qb_ws[(size_t)b * 256 + tid];
    maskLf[tid] = (tid < T_) ? ((mask[(size_t)b * T_ + tid] == 1) ? 1.0f : 0.0f) : 0.0f;
  }
  const float b3v = b3[0];

  // T14 prefetch registers: next chunk's keys (64 B/thread)
  float4 pk[4];

  // staging geometry (fixed per thread)
  const int sp0 = tid * 2, sp1 = tid * 2 + 1;
  const int srow0 = sp0 >> 4, sc0 = sp0 & 15;
  const int srow1 = sp1 >> 4, sc1 = sp1 & 15;

#define LOADK(CH)                                                          \
  {                                                                        \
    int t0_ = (CH) * 64 + srow0, t1_ = (CH) * 64 + srow1;                  \
    if (t0_ < T_) {                                                        \
      const float* kp = keys + ((size_t)b * T_ + t0_) * 128 + 8 * sc0;     \
      pk[0] = *(const float4*)kp; pk[1] = *(const float4*)(kp + 4);        \
    } else { pk[0] = make_float4(0,0,0,0); pk[1] = make_float4(0,0,0,0); } \
    if (t1_ < T_) {                                                        \
      const float* kp = keys + ((size_t)b * T_ + t1_) * 128 + 8 * sc1;     \
      pk[2] = *(const float4*)kp; pk[3] = *(const float4*)(kp + 4);        \
    } else { pk[2] = make_float4(0,0,0,0); pk[3] = make_float4(0,0,0,0); } \
  }

  LOADK(0);
  __syncthreads();

  const float qb0 = qbL[wid * 16 + (lane & 15)];
  const float qb1 = qbL[(wid + 8) * 16 + (lane & 15)];

  float na0 = 0.0f, na1 = 0.0f, da = 0.0f;

  for (int ch = 0; ch < 4; ++ch) {
    // ---- phase 1: convert prefetched keys -> Xc = [k, q*k] (bf16, swizzled) ----
    {
      float kv0[8] = {pk[0].x,pk[0].y,pk[0].z,pk[0].w,pk[1].x,pk[1].y,pk[1].z,pk[1].w};
      float kv1[8] = {pk[2].x,pk[2].y,pk[2].z,pk[2].w,pk[3].x,pk[3].y,pk[3].z,pk[3].w};
      s16x8 xk0, xq0, xk1, xq1;
#pragma unroll
      for (int j = 0; j < 8; ++j) {
        xk0[j] = (short)f2bf(kv0[j]);
        xq0[j] = (short)f2bf(kv0[j] * qL[8 * sc0 + j]);
        xk1[j] = (short)f2bf(kv1[j]);
        xq1[j] = (short)f2bf(kv1[j] * qL[8 * sc1 + j]);
      }
      const int sw0 = (srow0 & 7) << 3, sw1 = (srow1 & 7) << 3;
      *(s16x8*)&Xc[(srow0 * 256 + 8 * sc0) ^ sw0]       = xk0;
      *(s16x8*)&Xc[(srow0 * 256 + 128 + 8 * sc0) ^ sw0] = xq0;
      *(s16x8*)&Xc[(srow1 * 256 + 8 * sc1) ^ sw1]       = xk1;
      *(s16x8*)&Xc[(srow1 * 256 + 128 + 8 * sc1) ^ sw1] = xq1;
    }
    if (ch < 3) LOADK(ch + 1);     // issue next chunk's HBM loads early (T14)
    __syncthreads();

    const int rem = T_ - ch * 64;
    const int nrt = (rem >= 64) ? 4 : ((rem + 15) >> 4);

    // ---- phase 2: layer 1; wave owns cols {wid, wid+8} ----
    {
      s16x8 Bf0[8], Bf1[8];
#pragma unroll
      for (int s = 0; s < 8; ++s) {
        Bf0[s] = *(const s16x8*)(wcf + ((size_t)(wid * 8 + s) * 64 + lane) * 8);
        Bf1[s] = *(const s16x8*)(wcf + ((size_t)((wid + 8) * 8 + s) * 64 + lane) * 8);
      }
      const int asw = (lane & 7) << 3;
      for (int rt = 0; rt < nrt; ++rt) {
        const int abase = (rt * 16 + (lane & 15)) * 256 + (lane >> 4) * 8;
        f32x4 a0 = {0,0,0,0}, a1 = {0,0,0,0};
#pragma unroll
        for (int s = 0; s < 8; ++s) {
          s16x8 Af = *(const s16x8*)&Xc[(abase + s * 32) ^ asw];
          a0 = __builtin_amdgcn_mfma_f32_16x16x32_bf16(Af, Bf0[s], a0, 0, 0, 0);
          a1 = __builtin_amdgcn_mfma_f32_16x16x32_bf16(Af, Bf1[s], a1, 0, 0, 0);
        }
#pragma unroll
        for (int i = 0; i < 4; ++i) {
          int row = rt * 16 + (lane >> 4) * 4 + i;
          int sw = (row & 7) << 3;
          H1c[(row * 256 + wid * 16 + (lane & 15)) ^ sw]       = f2bf(sigf(a0[i] + qb0));
          H1c[(row * 256 + (wid + 8) * 16 + (lane & 15)) ^ sw] = f2bf(sigf(a1[i] + qb1));
        }
      }
    }
    __syncthreads();

    // ---- phase 3: layer2 + layer3 + mask -> ebuf (waves 0..3, full rows) ----
    if (wid < 4) {
      const int asw = (lane & 7) << 3;
      const int abase = (wid * 16 + (lane & 15)) * 256 + (lane >> 4) * 8;
      s16x8 Af[8];
#pragma unroll
      for (int s = 0; s < 8; ++s)
        Af[s] = *(const s16x8*)&H1c[(abase + s * 32) ^ asw];
      float p[4] = {0, 0, 0, 0};
#pragma unroll 2
      for (int cb = 0; cb < 8; ++cb) {
        f32x4 acc = {0, 0, 0, 0};
#pragma unroll
        for (int s = 0; s < 8; ++s) {
          s16x8 Bf = *(const s16x8*)(w2f + ((size_t)(cb * 8 + s) * 64 + lane) * 8);
          acc = __builtin_amdgcn_mfma_f32_16x16x32_bf16(Af[s], Bf, acc, 0, 0, 0);
        }
        const float b2v = b2L[cb * 16 + (lane & 15)];
        const float w3v = w3L[cb * 16 + (lane & 15)];
#pragma unroll
        for (int i = 0; i < 4; ++i)
          p[i] += sigf(acc[i] + b2v) * w3v;
      }
#pragma unroll
      for (int m = 1; m <= 8; m <<= 1)
#pragma unroll
        for (int i = 0; i < 4; ++i)
          p[i] += __shfl_xor(p[i], m);
      if ((lane & 15) == 0) {
#pragma unroll
        for (int i = 0; i < 4; ++i) {
          int row = wid * 16 + (lane >> 4) * 4 + i;
          ebuf[row] = maskLf[ch * 64 + row] * __expf(sigf(p[i] + b3v));
        }
      }
    }
    __syncthreads();

    // ---- phase 4: accumulate num/den; wave owns rows {wid*8 .. +8} ----
    {
      const unsigned* Xc32 = (const unsigned*)Xc;
#pragma unroll
      for (int r8 = 0; r8 < 8; ++r8) {
        const int row = wid * 8 + r8;
        const float ev = ebuf[row];          // wave-uniform
        if (ev != 0.0f) {
          da += ev;
          unsigned u = Xc32[(row * 128 + lane) ^ ((row & 7) << 2)];
          union { unsigned u; float f; } lo, hi;
          lo.u = u << 16;
          hi.u = u & 0xffff0000u;
          na0 += ev * lo.f;
          na1 += ev * hi.f;
        }
      }
    }
    __syncthreads();
  }

  // ---- final reduce across the 8 waves ----
  *(float2*)&numred[wid][2 * lane] = make_float2(na0, na1);
  if (lane == 0) denred[wid] = da;
  __syncthreads();
  if (tid < 128) {
    float num = 0.0f, den = 0.0f;
#pragma unroll
    for (int w = 0; w < 8; ++w) { num += numred[w][tid]; den += denred[w]; }
    out[(size_t)b * 128 + tid] = num / den;
  }
}

extern "C" void kernel_launch(void* const* d_in, const int* in_sizes, int n_in,
                              void* d_out, int out_size, void* d_ws, size_t ws_size,
                              hipStream_t stream) {
  const float* query = (const float*)d_in[0];
  const float* keys  = (const float*)d_in[1];
  const int*   mask  = (const int*)  d_in[2];
  const float* W1    = (const float*)d_in[3];
  const float* b1    = (const float*)d_in[4];
  const float* W2    = (const float*)d_in[5];
  const float* b2    = (const float*)d_in[6];
  const float* W3    = (const float*)d_in[7];
  const float* b3    = (const float*)d_in[8];
  float* out = (float*)d_out;

  char* ws = (char*)d_ws;
  unsigned short* wcf = (unsigned short*)(ws + WS_WCF);
  unsigned short* w2f = (unsigned short*)(ws + WS_W2F);
  float*          Q2  = (float*)(ws + WS_Q2);
  float*          qb  = (float*)(ws + WS_QB);

  prep_weights<<<80, 256, 0, stream>>>(W1, W2, wcf, w2f, Q2);
  qb_prep<<<256, 256, 0, stream>>>(query, b1, Q2, qb);
  attn_main<<<B_, 512, 0, stream>>>(query, keys, mask, wcf, w2f, qb,
                                    b2, W3, b3, out);
}

// Round 5
// 201.755 us; speedup vs baseline: 1.3026x; 1.3026x over previous
//
#include <hip/hip_runtime.h>
#include <hip/hip_bf16.h>

#define B_  2048
#define T_  200
#define D_  128
#define H1_ 256
#define H2_ 128
#define LOG2E 1.4426950408889634f

typedef __attribute__((ext_vector_type(8))) short  s16x8;
typedef __attribute__((ext_vector_type(4))) float  f32x4;

// ws layout (bytes)
#define WS_WCF   0         // bf16 Wc frags: 256x256 -> 131072 B
#define WS_W2F   131072    // bf16 W2 frags: 256x128 -> 65536 B
#define WS_Q2    196608    // f32 (W1b - W1c): 128x256 -> 131072 B
#define WS_QB    327680    // f32 qb: 2048x256 -> 2097152 B

__device__ __forceinline__ unsigned short f2bf(float f) {
  union { float f; unsigned u; } v; v.f = f;
  unsigned r = v.u + 0x7fffu + ((v.u >> 16) & 1u);
  return (unsigned short)(r >> 16);
}
__device__ __forceinline__ unsigned pkbf(float lo, float hi) {
  __hip_bfloat162 h = __float22bfloat162_rn(float2{lo, hi});
  union { __hip_bfloat162 h; unsigned u; } v; v.h = h;
  return v.u;
}
// sigmoid(a + c) with nc = -LOG2E*c precomputed: rcp(1+2^(-LOG2E*a + nc))
__device__ __forceinline__ float sig_fused(float a, float nc) {
  float t = __builtin_amdgcn_exp2f(__builtin_fmaf(a, -LOG2E, nc));
  return __builtin_amdgcn_rcpf(1.0f + t);
}

// ---------------- prep: weight fragments + Q2 ----------------
__global__ __launch_bounds__(256)
void prep_weights(const float* __restrict__ W1, const float* __restrict__ W2,
                  unsigned short* __restrict__ wcf, unsigned short* __restrict__ w2f,
                  float* __restrict__ Q2)
{
  int g = blockIdx.x * 256 + threadIdx.x;
  if (g < 8192) {
    int c = g >> 9, s = (g >> 6) & 7, l = g & 63;
    int col = 16 * c + (l & 15);
#pragma unroll
    for (int j = 0; j < 8; ++j) {
      int k = 32 * s + 8 * (l >> 4) + j;
      float v = W1[(256 + k) * H1_ + col];
      if (k < 128) v += W1[k * H1_ + col];
      wcf[(size_t)g * 8 + j] = f2bf(v);
    }
  } else if (g < 12288) {
    int g2 = g - 8192;
    int c = g2 >> 9, s = (g2 >> 6) & 7, l = g2 & 63;
    int col = 16 * c + (l & 15);
#pragma unroll
    for (int j = 0; j < 8; ++j) {
      int k = 32 * s + 8 * (l >> 4) + j;
      w2f[(size_t)g2 * 8 + j] = f2bf(W2[k * H2_ + col]);
    }
  } else {
    int g3 = g - 12288;
    int e = g3 * 4;
    int d = e >> 8, h = e & 255;
#pragma unroll
    for (int j = 0; j < 4; ++j)
      Q2[e + j] = W1[(128 + d) * H1_ + h + j] - W1[(256 + d) * H1_ + h + j];
  }
}

// ---------------- prep: qb[b][h] = b1[h] + q[b] @ Q2 ----------------
__global__ __launch_bounds__(256)
void qb_prep(const float* __restrict__ query, const float* __restrict__ b1,
             const float* __restrict__ Q2, float* __restrict__ qb)
{
  __shared__ float q8[8 * 128];
  int b0 = blockIdx.x * 8;
  int tid = threadIdx.x;
  {
    const float4 v = *(const float4*)(query + (size_t)b0 * 128 + tid * 4);
    *(float4*)(q8 + tid * 4) = v;
  }
  __syncthreads();
  int h = tid;
  float acc[8];
#pragma unroll
  for (int j = 0; j < 8; ++j) acc[j] = b1[h];
  for (int d = 0; d < 128; ++d) {
    float w = Q2[d * 256 + h];
#pragma unroll
    for (int j = 0; j < 8; ++j) acc[j] += q8[j * 128 + d] * w;
  }
#pragma unroll
  for (int j = 0; j < 8; ++j) qb[(size_t)(b0 + j) * 256 + h] = acc[j];
}

// ---------------- main ----------------
__global__ __launch_bounds__(512, 2)
void attn_main(const float* __restrict__ query, const float* __restrict__ keys,
               const int* __restrict__ mask,
               const unsigned short* __restrict__ wcf,
               const unsigned short* __restrict__ w2f,
               const float* __restrict__ qb_ws,
               const float* __restrict__ b2, const float* __restrict__ W3,
               const float* __restrict__ b3, float* __restrict__ out)
{
  __shared__ __align__(16) unsigned short Xc[64 * 256];   // 32KB swizzled
  __shared__ __align__(16) unsigned short H1c[64 * 256];  // 32KB swizzled
  __shared__ float qL[128];
  __shared__ float qbL[256];
  __shared__ float maskLf[256];
  __shared__ __align__(16) float scorep[64 * 4];
  __shared__ float numred[8][128];
  __shared__ float denred[8];

  const int b = blockIdx.x;
  const int tid = threadIdx.x;
  const int lane = tid & 63;
  const int wid = tid >> 6;

  if (tid < 128) qL[tid] = query[(size_t)b * 128 + tid];
  if (tid < 256) {
    qbL[tid] = qb_ws[(size_t)b * 256 + tid];
    maskLf[tid] = (tid < T_) ? ((mask[(size_t)b * T_ + tid] == 1) ? 1.0f : 0.0f) : 0.0f;
  }

  // ---- persistent weight fragments (loaded ONCE per block) ----
  // layer1: wave owns Wc col-blocks {wid, wid+8}
  // layer2: wave owns W2 col-blocks {c0, c1} x row-tiles {r0, r1}
  const int c0 = wid & 3, c1 = c0 + 4;
  const int r0 = (wid >> 2) * 2, r1 = r0 + 1;
  s16x8 Wc0[8], Wc1[8], W2a[8], W2b[8];
#pragma unroll
  for (int s = 0; s < 8; ++s) {
    Wc0[s] = *(const s16x8*)(wcf + ((size_t)(wid * 8 + s) * 64 + lane) * 8);
    Wc1[s] = *(const s16x8*)(wcf + ((size_t)((wid + 8) * 8 + s) * 64 + lane) * 8);
    W2a[s] = *(const s16x8*)(w2f + ((size_t)(c0 * 8 + s) * 64 + lane) * 8);
    W2b[s] = *(const s16x8*)(w2f + ((size_t)(c1 * 8 + s) * 64 + lane) * 8);
  }
  // fused-constant biases
  const float cb0 = -LOG2E * b2[c0 * 16 + (lane & 15)];
  const float cb1 = -LOG2E * b2[c1 * 16 + (lane & 15)];
  const float w3v0 = W3[c0 * 16 + (lane & 15)];
  const float w3v1 = W3[c1 * 16 + (lane & 15)];
  const float b3n = -LOG2E * b3[0];

  // staging geometry (fixed per thread)
  const int sp0 = tid * 2, sp1 = tid * 2 + 1;
  const int srow0 = sp0 >> 4, sc0s = sp0 & 15;
  const int srow1 = sp1 >> 4, sc1s = sp1 & 15;
  float4 pk[4];

#define LOADK(CH)                                                          \
  {                                                                        \
    int t0_ = (CH) * 64 + srow0, t1_ = (CH) * 64 + srow1;                  \
    if (t0_ < T_) {                                                        \
      const float* kp = keys + ((size_t)b * T_ + t0_) * 128 + 8 * sc0s;    \
      pk[0] = *(const float4*)kp; pk[1] = *(const float4*)(kp + 4);        \
    } else { pk[0] = make_float4(0,0,0,0); pk[1] = make_float4(0,0,0,0); } \
    if (t1_ < T_) {                                                        \
      const float* kp = keys + ((size_t)b * T_ + t1_) * 128 + 8 * sc1s;    \
      pk[2] = *(const float4*)kp; pk[3] = *(const float4*)(kp + 4);        \
    } else { pk[2] = make_float4(0,0,0,0); pk[3] = make_float4(0,0,0,0); } \
  }

  LOADK(0);
  __syncthreads();

  const float qn0 = -LOG2E * qbL[wid * 16 + (lane & 15)];
  const float qn1 = -LOG2E * qbL[(wid + 8) * 16 + (lane & 15)];

  float na0 = 0.0f, na1 = 0.0f, da = 0.0f;

  for (int ch = 0; ch < 4; ++ch) {
    const int rem = T_ - ch * 64;
    const int nrt = (rem >= 64) ? 4 : ((rem + 15) >> 4);

    // ---- P1: prefetched keys -> Xc = [k, q*k] bf16 (cvt_pk), swizzled ----
    {
      float kv0[8] = {pk[0].x,pk[0].y,pk[0].z,pk[0].w,pk[1].x,pk[1].y,pk[1].z,pk[1].w};
      float kv1[8] = {pk[2].x,pk[2].y,pk[2].z,pk[2].w,pk[3].x,pk[3].y,pk[3].z,pk[3].w};
      uint4 xk0, xq0, xk1, xq1;
      unsigned* xk0p = (unsigned*)&xk0; unsigned* xq0p = (unsigned*)&xq0;
      unsigned* xk1p = (unsigned*)&xk1; unsigned* xq1p = (unsigned*)&xq1;
#pragma unroll
      for (int j = 0; j < 4; ++j) {
        xk0p[j] = pkbf(kv0[2*j], kv0[2*j+1]);
        xq0p[j] = pkbf(kv0[2*j] * qL[8*sc0s + 2*j], kv0[2*j+1] * qL[8*sc0s + 2*j+1]);
        xk1p[j] = pkbf(kv1[2*j], kv1[2*j+1]);
        xq1p[j] = pkbf(kv1[2*j] * qL[8*sc1s + 2*j], kv1[2*j+1] * qL[8*sc1s + 2*j+1]);
      }
      const int sw0 = (srow0 & 7) << 3, sw1 = (srow1 & 7) << 3;
      *(uint4*)&Xc[(srow0 * 256 + 8 * sc0s) ^ sw0]       = xk0;
      *(uint4*)&Xc[(srow0 * 256 + 128 + 8 * sc0s) ^ sw0] = xq0;
      *(uint4*)&Xc[(srow1 * 256 + 8 * sc1s) ^ sw1]       = xk1;
      *(uint4*)&Xc[(srow1 * 256 + 128 + 8 * sc1s) ^ sw1] = xq1;
    }
    if (ch < 3) LOADK(ch + 1);     // T14: issue next chunk's HBM loads early
    __syncthreads();

    // ---- P2: layer 1, wave owns cols {wid, wid+8} ----
    {
      const int asw = (lane & 7) << 3;
      for (int rt = 0; rt < nrt; ++rt) {
        const int abase = (rt * 16 + (lane & 15)) * 256 + (lane >> 4) * 8;
        f32x4 a0 = {0,0,0,0}, a1 = {0,0,0,0};
#pragma unroll
        for (int s = 0; s < 8; ++s) {
          s16x8 Af = *(const s16x8*)&Xc[(abase + s * 32) ^ asw];
          a0 = __builtin_amdgcn_mfma_f32_16x16x32_bf16(Af, Wc0[s], a0, 0, 0, 0);
          a1 = __builtin_amdgcn_mfma_f32_16x16x32_bf16(Af, Wc1[s], a1, 0, 0, 0);
        }
#pragma unroll
        for (int i = 0; i < 4; ++i) {
          int row = rt * 16 + (lane >> 4) * 4 + i;
          int sw = (row & 7) << 3;
          H1c[(row * 256 + wid * 16 + (lane & 15)) ^ sw]       = f2bf(sig_fused(a0[i], qn0));
          H1c[(row * 256 + (wid + 8) * 16 + (lane & 15)) ^ sw] = f2bf(sig_fused(a1[i], qn1));
        }
      }
    }
    __syncthreads();

    // ---- P3: layer2+layer3 partials; wave owns rows {r0,r1} x cols {c0,c1} ----
    if (r0 * 16 < rem) {
      const int asw = (lane & 7) << 3;
      const int ab0 = (r0 * 16 + (lane & 15)) * 256 + (lane >> 4) * 8;
      const int ab1 = (r1 * 16 + (lane & 15)) * 256 + (lane >> 4) * 8;
      f32x4 a00 = {0,0,0,0}, a01 = {0,0,0,0}, a10 = {0,0,0,0}, a11 = {0,0,0,0};
#pragma unroll
      for (int s = 0; s < 8; ++s) {
        s16x8 A0 = *(const s16x8*)&H1c[(ab0 + s * 32) ^ asw];
        s16x8 A1 = *(const s16x8*)&H1c[(ab1 + s * 32) ^ asw];
        a00 = __builtin_amdgcn_mfma_f32_16x16x32_bf16(A0, W2a[s], a00, 0, 0, 0);
        a01 = __builtin_amdgcn_mfma_f32_16x16x32_bf16(A0, W2b[s], a01, 0, 0, 0);
        a10 = __builtin_amdgcn_mfma_f32_16x16x32_bf16(A1, W2a[s], a10, 0, 0, 0);
        a11 = __builtin_amdgcn_mfma_f32_16x16x32_bf16(A1, W2b[s], a11, 0, 0, 0);
      }
      float p0[4], p1[4];
#pragma unroll
      for (int i = 0; i < 4; ++i) {
        p0[i] = sig_fused(a00[i], cb0) * w3v0 + sig_fused(a01[i], cb1) * w3v1;
        p1[i] = sig_fused(a10[i], cb0) * w3v0 + sig_fused(a11[i], cb1) * w3v1;
      }
#pragma unroll
      for (int m = 1; m <= 8; m <<= 1)
#pragma unroll
        for (int i = 0; i < 4; ++i) {
          p0[i] += __shfl_xor(p0[i], m);
          p1[i] += __shfl_xor(p1[i], m);
        }
      if ((lane & 15) == 0) {
#pragma unroll
        for (int i = 0; i < 4; ++i) {
          int rr0 = r0 * 16 + (lane >> 4) * 4 + i;
          int rr1 = r1 * 16 + (lane >> 4) * 4 + i;
          scorep[rr0 * 4 + c0] = p0[i];
          scorep[rr1 * 4 + c0] = p1[i];
        }
      }
    }
    __syncthreads();

    // ---- P4: finalize e in-wave (lanes 0-7), accumulate num/den ----
    {
      float e = 0.0f;
      if (lane < 8) {
        const int row = wid * 8 + lane;
        const float4 s4 = *(const float4*)&scorep[row * 4];
        const float ssum = s4.x + s4.y + s4.z + s4.w;
        const float sc = sig_fused(ssum, b3n);
        e = maskLf[ch * 64 + row] * __builtin_amdgcn_exp2f(sc * LOG2E);
      }
      const unsigned* Xc32 = (const unsigned*)Xc;
#pragma unroll
      for (int r8 = 0; r8 < 8; ++r8) {
        const int row = wid * 8 + r8;
        const float ev = __shfl(e, r8);
        if (ev != 0.0f) {
          da += ev;
          unsigned u = Xc32[(row * 128 + lane) ^ ((row & 7) << 2)];
          union { unsigned u; float f; } lo, hi;
          lo.u = u << 16;
          hi.u = u & 0xffff0000u;
          na0 += ev * lo.f;
          na1 += ev * hi.f;
        }
      }
    }
    __syncthreads();
  }

  // ---- final reduce across the 8 waves ----
  *(float2*)&numred[wid][2 * lane] = make_float2(na0, na1);
  if (lane == 0) denred[wid] = da;
  __syncthreads();
  if (tid < 128) {
    float num = 0.0f, den = 0.0f;
#pragma unroll
    for (int w = 0; w < 8; ++w) { num += numred[w][tid]; den += denred[w]; }
    out[(size_t)b * 128 + tid] = num / den;
  }
}

extern "C" void kernel_launch(void* const* d_in, const int* in_sizes, int n_in,
                              void* d_out, int out_size, void* d_ws, size_t ws_size,
                              hipStream_t stream) {
  const float* query = (const float*)d_in[0];
  const float* keys  = (const float*)d_in[1];
  const int*   mask  = (const int*)  d_in[2];
  const float* W1    = (const float*)d_in[3];
  const float* b1    = (const float*)d_in[4];
  const float* W2    = (const float*)d_in[5];
  const float* b2    = (const float*)d_in[6];
  const float* W3    = (const float*)d_in[7];
  const float* b3    = (const float*)d_in[8];
  float* out = (float*)d_out;

  char* ws = (char*)d_ws;
  unsigned short* wcf = (unsigned short*)(ws + WS_WCF);
  unsigned short* w2f = (unsigned short*)(ws + WS_W2F);
  float*          Q2  = (float*)(ws + WS_Q2);
  float*          qb  = (float*)(ws + WS_QB);

  prep_weights<<<80, 256, 0, stream>>>(W1, W2, wcf, w2f, Q2);
  qb_prep<<<256, 256, 0, stream>>>(query, b1, Q2, qb);
  attn_main<<<B_, 512, 0, stream>>>(query, keys, mask, wcf, w2f, qb,
                                    b2, W3, b3, out);
}